// Round 1
// baseline (173.780 us; speedup 1.0000x reference)
//
#include <hip/hip_runtime.h>

// DCN: B=4, C=64, H=W=128, Cout=64, 3x3, pad=1, stride=1, dil=1
#define B_   4
#define C_   64
#define H_   128
#define W_   128
#define OC_  64
#define K_   9
#define OCH_ 18
#define CK_  576

#define S_    104            // Pl row stride in halfs (208 B, 16B-aligned)
#define WCOLS 768            // 8 chunks * 96 padded cols
#define XSW   72             // window cols (64 + 2*4 halo)
#define XSH   7              // window rows (ho-3 .. ho+3)
#define XSC   (XSH*XSW)      // 504 floats per channel (phase-2 layout)
#define XSC1  (3*XSW)        // 216 floats per channel (phase-1 dense layout)
#define XSB1  1728           // floats per phase-1 DMA buffer (two fit in XS2)
#define XS2   4032           // floats: phase-2 SINGLE staging buffer (16128 B)
#define NS2   1008           // 8ch*7row*18 float4 slots
#define NS1   432            // 8ch*3row*18 float4 slots

#define WPAD_HALFS  (OC_*WCOLS)              // 49152
#define W0PAD_HALFS (32*WCOLS)               // 24576
#define ZPAGE_BYTE  (2*WPAD_HALFS + 2*W0PAD_HALFS)   // 147456 (16B aligned)

using half8v  = __attribute__((ext_vector_type(8))) _Float16;
using half2v  = __attribute__((ext_vector_type(2))) _Float16;
using float4v = __attribute__((ext_vector_type(4))) float;

// async 16B global->LDS DMA (no VGPR round-trip; drained by vmcnt at barriers)
#define GLDS16(SRC, DST)                                              \
    __builtin_amdgcn_global_load_lds(                                 \
        (__attribute__((address_space(1))) void*)(SRC),               \
        (__attribute__((address_space(3))) void*)(DST), 16, 0, 0)

// ---------------------------------------------------------------------------
// k0: cast+pad weights to f16 in MFMA-chunk layout; zero the OOB page.
// col = cc*96 + kk*8 + cl  (channel c = cc*8+cl, tap kk; kk>=9 -> 0)
// ---------------------------------------------------------------------------
__global__ void k0_prep(const float* __restrict__ w, const float* __restrict__ ow,
                        _Float16* __restrict__ wpad, _Float16* __restrict__ w0pad,
                        float* __restrict__ zp) {
    if (blockIdx.x == 0 && threadIdx.x < 64) zp[threadIdx.x] = 0.f;
    int i = blockIdx.x * 256 + threadIdx.x;
    if (i < OC_ * WCOLS) {
        int oc = i / WCOLS, col = i - oc * WCOLS;
        int cc = col / 96, r = col - cc * 96;
        int kk = r >> 3, cl = r & 7;
        float v = 0.f;
        if (kk < 9) v = w[oc * CK_ + (cc * 8 + cl) * 9 + kk];
        wpad[i] = (_Float16)v;
    } else {
        int j = i - OC_ * WCOLS;
        if (j < 32 * WCOLS) {
            int rr = j / WCOLS, col = j - rr * WCOLS;
            int cc = col / 96, r = col - cc * 96;
            int kk = r >> 3, cl = r & 7;
            float v = 0.f;
            if (rr < OCH_ && kk < 9) v = ow[rr * CK_ + (cc * 8 + cl) * 9 + kk];
            w0pad[j] = (_Float16)v;
        }
    }
}

// ---------------------------------------------------------------------------
// k_fused: phase1 offset conv (DMA-double-buffered staging inside the single
// 16 KB window buffer) -> offs in LDS -> phase2 bilinear sample + main conv.
// Phase-2 staging is register-staged (T14: global->reg early, ds_write after
// the Pl barrier, overlapping MFMA) so ONE 16 KB window buffer suffices.
// Block = 64 oc x 64 pix.  LDS 34048 B -> 4 blocks/CU (grid = 4 blocks/CU
// exactly: single occupancy round; was 3/CU -> 3+1 rounds).
// ---------------------------------------------------------------------------
__global__ __launch_bounds__(256, 4) void k_fused(
    const float* __restrict__ x, const _Float16* __restrict__ wpad,
    const _Float16* __restrict__ w0pad, const float* __restrict__ bias,
    const float* __restrict__ ob, const float* __restrict__ zp,
    float* __restrict__ out)
{
    __shared__ __align__(16) float    xs[XS2];       // 16128 B (single buffer)
    __shared__ __align__(16) _Float16 Pl[64 * S_];   // 13312 B
    __shared__ float offs_lds[OCH_ * 64];            //  4608 B

    // ---- XCD-aware work decode ----
    const int g   = blockIdx.x;
    const int xcd = g & 7;
    const int n   = g >> 3;
    const int hb  = n & 1;
    const int hol = (n >> 1) & 15;
    const int b   = n >> 5;
    const int ho  = xcd * 16 + hol;

    const int t = threadIdx.x, lane = t & 63, w = t >> 6;
    const int lr = lane & 15, q = lane >> 4;
    const int lpix = w * 16 + lr;            // this thread's pixel
    const int po   = hb * 64 + lpix;
    const int start = hb * 64 - 4;
    const float* xb = x + ((long)b << 20);

    // zero Pl pad cols 72..95 once
    for (int i = t; i < 64 * 12; i += 256) {
        int row = i / 12, j = i - row * 12;
        *(unsigned*)&Pl[row * S_ + 72 + 2 * j] = 0u;
    }

    // ---- staging slot descriptors (decoded once) ----
    // phase-1: rows ho-1..ho+1, dense 3-row layout (432 slots, 2/thread)
    int g1o[2]; bool g1k[2], g1v[2];
#pragma unroll
    for (int s = 0; s < 2; s++) {
        int idx = t + 256 * s;
        g1v[s] = idx < NS1;
        int ii = g1v[s] ? idx : 0;
        int c  = ii / 54, rj = ii - c * 54;
        int r3 = rj / 18, jc = rj - r3 * 18;
        int gy = ho - 1 + r3, gx = start + 4 * jc;
        g1k[s] = ((unsigned)gy < (unsigned)H_) && (gx >= 0) && (gx + 3 < W_);
        g1o[s] = (c << 14) + (gy << 7) + gx;
    }
    // phase-2: rows ho-3..ho+3, full 7-row layout (1008 slots, 4/thread)
    int g2o[4]; bool g2k[4], g2v[4];
#pragma unroll
    for (int s = 0; s < 4; s++) {
        int idx = t + 256 * s;
        g2v[s] = idx < NS2;
        int ii = g2v[s] ? idx : 0;
        int c  = ii / 126, rj = ii - c * 126;
        int r  = rj / 18, jc = rj - r * 18;
        int gy = ho - 3 + r, gx = start + 4 * jc;
        g2k[s] = ((unsigned)gy < (unsigned)H_) && (gx >= 0) && (gx + 3 < W_);
        g2o[s] = (c << 14) + (gy << 7) + gx;
    }

    // ================= phase 1: offset conv =================
    // prologue: stage chunk 0 (async DMA into buf0 = xs[0..])
#pragma unroll
    for (int s = 0; s < 2; s++) if (g1v[s])
        GLDS16(g1k[s] ? (xb + g1o[s]) : zp, xs + 4 * (t + 256 * s));

    float4v oa0 = {0.f,0.f,0.f,0.f}, oa1 = {0.f,0.f,0.f,0.f};

    for (int cc = 0; cc < 8; cc++) {
        __syncthreads();                       // (A) buf[cc&1] ready (drains DMA)
        if (cc < 7) {
            float* dst = xs + ((cc + 1) & 1) * XSB1;
            const float* srcb = xb + ((long)(cc + 1) << 17);
#pragma unroll
            for (int s = 0; s < 2; s++) if (g1v[s])
                GLDS16(g1k[s] ? (srcb + g1o[s]) : zp, dst + 4 * (t + 256 * s));
        }
        // im2col from LDS window: channels 2q, 2q+1 at pixel lpix
        {
            const float* b0 = xs + (cc & 1) * XSB1 + (2 * q) * XSC1;
            const float* b1 = b0 + XSC1;
#pragma unroll
            for (int ky = 0; ky < 3; ky++) {
#pragma unroll
                for (int kx = 0; kx < 3; kx++) {
                    float u0 = b0[ky * XSW + lpix + 3 + kx];
                    float u1 = b1[ky * XSW + lpix + 3 + kx];
                    half2v hv = {(_Float16)u0, (_Float16)u1};
                    *(half2v*)&Pl[lpix * S_ + (ky * 3 + kx) * 8 + 2 * q] = hv;
                }
            }
        }
        __syncthreads();                       // (B) Pl ready (also drains stage cc+1)
#pragma unroll
        for (int ks = 0; ks < 3; ks++) {
            half8v a0 = *(const half8v*)&w0pad[lr * WCOLS + cc * 96 + ks * 32 + q * 8];
            half8v a1 = *(const half8v*)&w0pad[(16 + lr) * WCOLS + cc * 96 + ks * 32 + q * 8];
            half8v bv = *(const half8v*)&Pl[lpix * S_ + ks * 32 + q * 8];
            oa0 = __builtin_amdgcn_mfma_f32_16x16x32_f16(a0, bv, oa0, 0, 0, 0);
            oa1 = __builtin_amdgcn_mfma_f32_16x16x32_f16(a1, bv, oa1, 0, 0, 0);
        }
    }

    // offsets -> LDS
#pragma unroll
    for (int r = 0; r < 4; r++) {
        int ch = q * 4 + r;
        offs_lds[ch * 64 + lpix] = oa0[r] + ob[ch];
    }
#pragma unroll
    for (int r = 0; r < 4; r++) {
        int ch = 16 + q * 4 + r;
        if (ch < OCH_) offs_lds[ch * 64 + lpix] = oa1[r] + ob[ch];
    }
    __syncthreads();                           // (C) offs ready

    // phase-2 prologue: issue chunk-0 DMA, then meta (overlaps DMA latency)
#pragma unroll
    for (int s = 0; s < 4; s++) if (g2v[s])
        GLDS16(g2k[s] ? (xb + g2o[s]) : zp, xs + 4 * (t + 256 * s));

    unsigned moff[9];
    float mw0[9], mw1[9], mw2[9], mw3[9];
    unsigned okm = 0;
#pragma unroll
    for (int kk = 0; kk < 9; kk++) {
        int ky = kk / 3, kx = kk - 3 * ky;
        float dy = offs_lds[(2 * kk) * 64 + lpix];
        float dx = offs_lds[(2 * kk + 1) * 64 + lpix];
        float py = (float)(ho - 1 + ky) + dy;
        float px = (float)(po - 1 + kx) + dx;
        float fy = floorf(py), fx = floorf(px);
        float ly = py - fy, lx = px - fx;
        int y0 = (int)fy, x0 = (int)fx;
        int y1 = y0 + 1, x1 = x0 + 1;
        float vy0 = ((unsigned)y0 < (unsigned)H_) ? 1.f : 0.f;
        float vy1 = ((unsigned)y1 < (unsigned)H_) ? 1.f : 0.f;
        float vx0 = ((unsigned)x0 < (unsigned)W_) ? 1.f : 0.f;
        float vx1 = ((unsigned)x1 < (unsigned)W_) ? 1.f : 0.f;
        float w00 = (1.f - ly) * (1.f - lx) * vy0 * vx0;
        float w01 = (1.f - ly) * lx * vy0 * vx1;
        float w10 = ly * (1.f - lx) * vy1 * vx0;
        float w11 = ly * lx * vy1 * vx1;
        int cy0 = min(max(y0, 0), H_ - 1);
        int cy1 = min(max(y1, 0), H_ - 1);
        int xl  = min(max(x0, 0), W_ - 2);
        bool noswap = (x0 == xl);              // fold x-clamp into weight swap
        mw0[kk] = noswap ? w00 : w01;
        mw1[kk] = noswap ? w01 : w00;
        mw2[kk] = noswap ? w10 : w11;
        mw3[kk] = noswap ? w11 : w10;
        int sy0 = cy0 - (ho - 3);
        int sy1 = cy1 - (ho - 3);
        int sx  = xl - start;
        bool ok = ((unsigned)sy0 < (unsigned)XSH) && ((unsigned)sy1 < (unsigned)XSH)
               && ((unsigned)sx < (unsigned)(XSW - 1));
        okm |= (ok ? 1u : 0u) << kk;
        moff[kk] = (unsigned)(sy0 * XSW + sx) | ((unsigned)(sy1 * XSW + sx) << 16);
    }

    // ================= phase 2: sample + main conv =================
    // Single staging buffer: global->reg loads issued at top of iteration
    // (HBM/L2 latency hides under the ~72-read sampling phase), ds_write
    // after barrier (B) overlaps the MFMA cluster. Barrier (A) of the next
    // iteration drains lgkmcnt, so no extra syncs are needed.
    float4v a00 = {0.f,0.f,0.f,0.f}, a01 = {0.f,0.f,0.f,0.f};
    float4v a10 = {0.f,0.f,0.f,0.f}, a11 = {0.f,0.f,0.f,0.f};
    const int wm = w & 1, wn = w >> 1;

    for (int cc = 0; cc < 8; cc++) {
        __syncthreads();                       // (A) xs = chunk cc (cc=0: drains
                                               //     DMA; cc>0: drains ds_writes)
        float4v st[4];
        if (cc < 7) {                          // issue next-chunk loads -> regs
            const float* srcb = xb + ((long)(cc + 1) << 17);
#pragma unroll
            for (int s = 0; s < 4; s++) if (g2v[s])
                st[s] = *(const float4v*)(g2k[s] ? (srcb + g2o[s]) : zp);
        }
        // sample channels 2q, 2q+1 at pixel lpix
        const float* xs0 = xs + (2 * q) * XSC;
        const float* xs1 = xs0 + XSC;
        if (__all(okm == 0x1FFu)) {
#pragma unroll
            for (int kk = 0; kk < 9; kk++) {
                int A  = (int)(moff[kk] & 0xFFFFu);
                int Bo = (int)(moff[kk] >> 16);
                float p0 = xs0[A] * mw0[kk] + xs0[A + 1] * mw1[kk]
                         + xs0[Bo] * mw2[kk] + xs0[Bo + 1] * mw3[kk];
                float p1 = xs1[A] * mw0[kk] + xs1[A + 1] * mw1[kk]
                         + xs1[Bo] * mw2[kk] + xs1[Bo + 1] * mw3[kk];
                half2v hv = {(_Float16)p0, (_Float16)p1};
                *(half2v*)&Pl[lpix * S_ + kk * 8 + 2 * q] = hv;
            }
        } else {
            // rare big-offset fallback: gather from global (clamped, valid)
            const float* xc0 = xb + ((long)(cc * 8 + 2 * q) << 14);
            const float* xc1 = xc0 + (1 << 14);
#pragma unroll
            for (int kk = 0; kk < 9; kk++) {
                int ky = kk / 3, kx = kk - 3 * ky;
                float dy = offs_lds[(2 * kk) * 64 + lpix];
                float dx = offs_lds[(2 * kk + 1) * 64 + lpix];
                float py = (float)(ho - 1 + ky) + dy;
                float px = (float)(po - 1 + kx) + dx;
                int y0 = (int)floorf(py), x0 = (int)floorf(px);
                int cy0 = min(max(y0, 0), H_ - 1);
                int cy1 = min(max(y0 + 1, 0), H_ - 1);
                int xl  = min(max(x0, 0), W_ - 2);
                int ga = (cy0 << 7) + xl, gb = (cy1 << 7) + xl;
                float p0 = xc0[ga] * mw0[kk] + xc0[ga + 1] * mw1[kk]
                         + xc0[gb] * mw2[kk] + xc0[gb + 1] * mw3[kk];
                float p1 = xc1[ga] * mw0[kk] + xc1[ga + 1] * mw1[kk]
                         + xc1[gb] * mw2[kk] + xc1[gb + 1] * mw3[kk];
                half2v hv = {(_Float16)p0, (_Float16)p1};
                *(half2v*)&Pl[lpix * S_ + kk * 8 + 2 * q] = hv;
            }
        }
        __syncthreads();                       // (B) Pl ready + all xs reads done
        if (cc < 7) {                          // commit staged chunk cc+1 -> xs
                                               // (overlaps MFMA; lane stride 16
                                               //  dwords = uniform 8/bank, no
                                               //  conflicts beyond b128 floor)
#pragma unroll
            for (int s = 0; s < 4; s++) if (g2v[s])
                *(float4v*)(xs + 4 * (t + 256 * s)) = st[s];
        }
#pragma unroll
        for (int ks = 0; ks < 3; ks++) {
            half8v A0 = *(const half8v*)&wpad[(wm * 32 + lr) * WCOLS + cc * 96 + ks * 32 + q * 8];
            half8v A1 = *(const half8v*)&wpad[(wm * 32 + 16 + lr) * WCOLS + cc * 96 + ks * 32 + q * 8];
            half8v B0 = *(const half8v*)&Pl[(wn * 32 + lr) * S_ + ks * 32 + q * 8];
            half8v B1 = *(const half8v*)&Pl[(wn * 32 + 16 + lr) * S_ + ks * 32 + q * 8];
            a00 = __builtin_amdgcn_mfma_f32_16x16x32_f16(A0, B0, a00, 0, 0, 0);
            a01 = __builtin_amdgcn_mfma_f32_16x16x32_f16(A0, B1, a01, 0, 0, 0);
            a10 = __builtin_amdgcn_mfma_f32_16x16x32_f16(A1, B0, a10, 0, 0, 0);
            a11 = __builtin_amdgcn_mfma_f32_16x16x32_f16(A1, B1, a11, 0, 0, 0);
        }
    }

    // ---- epilogue ----
    const int pixc = hb * 64 + wn * 32 + lr;
#pragma unroll
    for (int r = 0; r < 4; r++) {
        int oc0 = wm * 32 + q * 4 + r;
        int oc1 = oc0 + 16;
        float* o0 = out + (((long)(b * OC_ + oc0)) << 14) + (ho << 7);
        float* o1 = out + (((long)(b * OC_ + oc1)) << 14) + (ho << 7);
        o0[pixc]      = a00[r] + bias[oc0];
        o0[pixc + 16] = a01[r] + bias[oc0];
        o1[pixc]      = a10[r] + bias[oc1];
        o1[pixc + 16] = a11[r] + bias[oc1];
    }
}

// ---------------------------------------------------------------------------
extern "C" void kernel_launch(void* const* d_in, const int* in_sizes, int n_in,
                              void* d_out, int out_size, void* d_ws, size_t ws_size,
                              hipStream_t stream) {
    const float* x  = (const float*)d_in[0];
    const float* wt = (const float*)d_in[1];
    const float* bi = (const float*)d_in[2];
    const float* ow = (const float*)d_in[3];
    const float* ob = (const float*)d_in[4];
    float* out = (float*)d_out;

    _Float16* wpad  = (_Float16*)d_ws;
    _Float16* w0pad = wpad + WPAD_HALFS;
    float*    zp    = (float*)((char*)d_ws + ZPAGE_BYTE);

    k0_prep<<<(OC_ * WCOLS + 32 * WCOLS + 255) / 256, 256, 0, stream>>>(wt, ow, wpad, w0pad, zp);
    k_fused<<<B_ * H_ * 2, 256, 0, stream>>>(x, wpad, w0pad, bi, ob, zp, out);
}

// Round 2
// 138.533 us; speedup vs baseline: 1.2544x; 1.2544x over previous
//
#include <hip/hip_runtime.h>

// DCN: B=4, C=64, H=W=128, Cout=64, 3x3, pad=1, stride=1, dil=1
#define B_   4
#define C_   64
#define H_   128
#define W_   128
#define OC_  64
#define K_   9
#define OCH_ 18
#define CK_  576

#define S_    104            // Pl row stride in halfs (208 B, 16B-aligned)
#define WCOLS 768            // 8 chunks * 96 padded cols
#define XSW   72             // window cols (64 + 2*4 halo)
#define XSH   7              // window rows (ho-3 .. ho+3)
#define XSC   (XSH*XSW)      // 504 floats per channel (phase-2 layout)
#define XSC1  (3*XSW)        // 216 floats per channel (phase-1 dense layout)
#define XSB1  1728           // floats per phase-1 DMA buffer
#define XSB2  2016           // floats per phase-2 half-stage buffer (4 ch)
#define XSTOT 4032           // floats total staging region (16128 B)
#define NS2H  504            // 4ch*7row*18 float4 slots per half-stage
#define NS1   432            // 8ch*3row*18 float4 slots

#define WPAD_HALFS  (OC_*WCOLS)              // 49152
#define W0PAD_HALFS (32*WCOLS)               // 24576
#define ZPAGE_BYTE  (2*WPAD_HALFS + 2*W0PAD_HALFS)   // 147456 (16B aligned)

using half8v  = __attribute__((ext_vector_type(8))) _Float16;
using half2v  = __attribute__((ext_vector_type(2))) _Float16;
using float4v = __attribute__((ext_vector_type(4))) float;

// async 16B global->LDS DMA (no VGPR round-trip; drained by vmcnt at barriers)
#define GLDS16(SRC, DST)                                              \
    __builtin_amdgcn_global_load_lds(                                 \
        (__attribute__((address_space(1))) void*)(SRC),               \
        (__attribute__((address_space(3))) void*)(DST), 16, 0, 0)

// ---------------------------------------------------------------------------
// k0: cast+pad weights to f16 in MFMA-chunk layout; zero the OOB page.
// col = cc*96 + kk*8 + cl  (channel c = cc*8+cl, tap kk; kk>=9 -> 0)
// ---------------------------------------------------------------------------
__global__ void k0_prep(const float* __restrict__ w, const float* __restrict__ ow,
                        _Float16* __restrict__ wpad, _Float16* __restrict__ w0pad,
                        float* __restrict__ zp) {
    if (blockIdx.x == 0 && threadIdx.x < 64) zp[threadIdx.x] = 0.f;
    int i = blockIdx.x * 256 + threadIdx.x;
    if (i < OC_ * WCOLS) {
        int oc = i / WCOLS, col = i - oc * WCOLS;
        int cc = col / 96, r = col - cc * 96;
        int kk = r >> 3, cl = r & 7;
        float v = 0.f;
        if (kk < 9) v = w[oc * CK_ + (cc * 8 + cl) * 9 + kk];
        wpad[i] = (_Float16)v;
    } else {
        int j = i - OC_ * WCOLS;
        if (j < 32 * WCOLS) {
            int rr = j / WCOLS, col = j - rr * WCOLS;
            int cc = col / 96, r = col - cc * 96;
            int kk = r >> 3, cl = r & 7;
            float v = 0.f;
            if (rr < OCH_ && kk < 9) v = ow[rr * CK_ + (cc * 8 + cl) * 9 + kk];
            w0pad[j] = (_Float16)v;
        }
    }
}

// ---------------------------------------------------------------------------
// k_fused: phase1 offset conv (DMA double-buffer, 3-row windows) -> offs in
// LDS -> phase2 bilinear sample + main conv with DMA double-buffer at
// HALF-CHUNK (4-channel) granularity: two 8064 B buffers fit in the same
// 16128 B region a full chunk needs, so LDS stays at 34048 B -> 4 blocks/CU
// (grid = 4 blocks/CU exactly: one occupancy round) with NO register staging
// (r1's reg-staged variant spilled: WRITE_SIZE 16->48 MB).
// ---------------------------------------------------------------------------
__global__ __launch_bounds__(256, 3) void k_fused(
    const float* __restrict__ x, const _Float16* __restrict__ wpad,
    const _Float16* __restrict__ w0pad, const float* __restrict__ bias,
    const float* __restrict__ ob, const float* __restrict__ zp,
    float* __restrict__ out)
{
    __shared__ __align__(16) float    xs[XSTOT];     // 16128 B staging region
    __shared__ __align__(16) _Float16 Pl[64 * S_];   // 13312 B
    __shared__ float offs_lds[OCH_ * 64];            //  4608 B

    // ---- XCD-aware work decode ----
    const int g   = blockIdx.x;
    const int xcd = g & 7;
    const int n   = g >> 3;
    const int hb  = n & 1;
    const int hol = (n >> 1) & 15;
    const int b   = n >> 5;
    const int ho  = xcd * 16 + hol;

    const int t = threadIdx.x, lane = t & 63, w = t >> 6;
    const int lr = lane & 15, q = lane >> 4;
    const int lpix = w * 16 + lr;            // this thread's pixel
    const int po   = hb * 64 + lpix;
    const int start = hb * 64 - 4;
    const float* xb = x + ((long)b << 20);

    // zero Pl pad cols 72..95 once
    for (int i = t; i < 64 * 12; i += 256) {
        int row = i / 12, j = i - row * 12;
        *(unsigned*)&Pl[row * S_ + 72 + 2 * j] = 0u;
    }

    // ---- staging slot descriptors (decoded once) ----
    // phase-1: rows ho-1..ho+1, dense 3-row layout (432 slots, 2/thread)
    int g1o[2]; bool g1k[2], g1v[2];
#pragma unroll
    for (int s = 0; s < 2; s++) {
        int idx = t + 256 * s;
        g1v[s] = idx < NS1;
        int ii = g1v[s] ? idx : 0;
        int c  = ii / 54, rj = ii - c * 54;
        int r3 = rj / 18, jc = rj - r3 * 18;
        int gy = ho - 1 + r3, gx = start + 4 * jc;
        g1k[s] = ((unsigned)gy < (unsigned)H_) && (gx >= 0) && (gx + 3 < W_);
        g1o[s] = (c << 14) + (gy << 7) + gx;
    }
    // phase-2 half-stage: 4 channels x rows ho-3..ho+3 (504 slots, 2/thread)
    int g2o[2]; bool g2k[2], g2v[2];
#pragma unroll
    for (int s = 0; s < 2; s++) {
        int idx = t + 256 * s;
        g2v[s] = idx < NS2H;
        int ii = g2v[s] ? idx : 0;
        int c  = ii / 126, rj = ii - c * 126;    // c = channel 0..3 in half-stage
        int r  = rj / 18, jc = rj - r * 18;
        int gy = ho - 3 + r, gx = start + 4 * jc;
        g2k[s] = ((unsigned)gy < (unsigned)H_) && (gx >= 0) && (gx + 3 < W_);
        g2o[s] = (c << 14) + (gy << 7) + gx;
    }

    // ================= phase 1: offset conv =================
    // prologue: stage chunk 0 (async DMA into buf0 = xs[0..])
#pragma unroll
    for (int s = 0; s < 2; s++) if (g1v[s])
        GLDS16(g1k[s] ? (xb + g1o[s]) : zp, xs + 4 * (t + 256 * s));

    float4v oa0 = {0.f,0.f,0.f,0.f}, oa1 = {0.f,0.f,0.f,0.f};

    for (int cc = 0; cc < 8; cc++) {
        __syncthreads();                       // (A) buf[cc&1] ready (drains DMA)
        if (cc < 7) {
            float* dst = xs + ((cc + 1) & 1) * XSB1;
            const float* srcb = xb + ((long)(cc + 1) << 17);
#pragma unroll
            for (int s = 0; s < 2; s++) if (g1v[s])
                GLDS16(g1k[s] ? (srcb + g1o[s]) : zp, dst + 4 * (t + 256 * s));
        }
        // im2col from LDS window: channels 2q, 2q+1 at pixel lpix
        {
            const float* b0 = xs + (cc & 1) * XSB1 + (2 * q) * XSC1;
            const float* b1 = b0 + XSC1;
#pragma unroll
            for (int ky = 0; ky < 3; ky++) {
#pragma unroll
                for (int kx = 0; kx < 3; kx++) {
                    float u0 = b0[ky * XSW + lpix + 3 + kx];
                    float u1 = b1[ky * XSW + lpix + 3 + kx];
                    half2v hv = {(_Float16)u0, (_Float16)u1};
                    *(half2v*)&Pl[lpix * S_ + (ky * 3 + kx) * 8 + 2 * q] = hv;
                }
            }
        }
        __syncthreads();                       // (B) Pl ready (also drains stage cc+1)
#pragma unroll
        for (int ks = 0; ks < 3; ks++) {
            half8v a0 = *(const half8v*)&w0pad[lr * WCOLS + cc * 96 + ks * 32 + q * 8];
            half8v a1 = *(const half8v*)&w0pad[(16 + lr) * WCOLS + cc * 96 + ks * 32 + q * 8];
            half8v bv = *(const half8v*)&Pl[lpix * S_ + ks * 32 + q * 8];
            oa0 = __builtin_amdgcn_mfma_f32_16x16x32_f16(a0, bv, oa0, 0, 0, 0);
            oa1 = __builtin_amdgcn_mfma_f32_16x16x32_f16(a1, bv, oa1, 0, 0, 0);
        }
    }

    // offsets -> LDS
#pragma unroll
    for (int r = 0; r < 4; r++) {
        int ch = q * 4 + r;
        offs_lds[ch * 64 + lpix] = oa0[r] + ob[ch];
    }
#pragma unroll
    for (int r = 0; r < 4; r++) {
        int ch = 16 + q * 4 + r;
        if (ch < OCH_) offs_lds[ch * 64 + lpix] = oa1[r] + ob[ch];
    }
    __syncthreads();                           // (C) offs ready

    // phase-2 prologue: issue half-stage-0 DMA, then meta (overlaps DMA latency)
#pragma unroll
    for (int s = 0; s < 2; s++) if (g2v[s])
        GLDS16(g2k[s] ? (xb + g2o[s]) : zp, xs + 4 * (t + 256 * s));

    unsigned moff[9];
    float mw0[9], mw1[9], mw2[9], mw3[9];
    unsigned okm = 0;
#pragma unroll
    for (int kk = 0; kk < 9; kk++) {
        int ky = kk / 3, kx = kk - 3 * ky;
        float dy = offs_lds[(2 * kk) * 64 + lpix];
        float dx = offs_lds[(2 * kk + 1) * 64 + lpix];
        float py = (float)(ho - 1 + ky) + dy;
        float px = (float)(po - 1 + kx) + dx;
        float fy = floorf(py), fx = floorf(px);
        float ly = py - fy, lx = px - fx;
        int y0 = (int)fy, x0 = (int)fx;
        int y1 = y0 + 1, x1 = x0 + 1;
        float vy0 = ((unsigned)y0 < (unsigned)H_) ? 1.f : 0.f;
        float vy1 = ((unsigned)y1 < (unsigned)H_) ? 1.f : 0.f;
        float vx0 = ((unsigned)x0 < (unsigned)W_) ? 1.f : 0.f;
        float vx1 = ((unsigned)x1 < (unsigned)W_) ? 1.f : 0.f;
        float w00 = (1.f - ly) * (1.f - lx) * vy0 * vx0;
        float w01 = (1.f - ly) * lx * vy0 * vx1;
        float w10 = ly * (1.f - lx) * vy1 * vx0;
        float w11 = ly * lx * vy1 * vx1;
        int cy0 = min(max(y0, 0), H_ - 1);
        int cy1 = min(max(y1, 0), H_ - 1);
        int xl  = min(max(x0, 0), W_ - 2);
        bool noswap = (x0 == xl);              // fold x-clamp into weight swap
        mw0[kk] = noswap ? w00 : w01;
        mw1[kk] = noswap ? w01 : w00;
        mw2[kk] = noswap ? w10 : w11;
        mw3[kk] = noswap ? w11 : w10;
        int sy0 = cy0 - (ho - 3);
        int sy1 = cy1 - (ho - 3);
        int sx  = xl - start;
        bool ok = ((unsigned)sy0 < (unsigned)XSH) && ((unsigned)sy1 < (unsigned)XSH)
               && ((unsigned)sx < (unsigned)(XSW - 1));
        okm |= (ok ? 1u : 0u) << kk;
        moff[kk] = (unsigned)(sy0 * XSW + sx) | ((unsigned)(sy1 * XSW + sx) << 16);
    }

    // ================= phase 2: sample + main conv =================
    // half-stage h covers channels 4h..4h+3 in buf[h&1]; each thread samples
    // ONE channel (4h+q) at its pixel; MFMA for chunk cc fires after half-
    // stage 2cc+1. DMA for h+1 issued right after barrier (A) of h.
    float4v a00 = {0.f,0.f,0.f,0.f}, a01 = {0.f,0.f,0.f,0.f};
    float4v a10 = {0.f,0.f,0.f,0.f}, a11 = {0.f,0.f,0.f,0.f};
    const int wm = w & 1, wn = w >> 1;

    auto sample_half = [&](int h) {
        const int hf = h & 1;
        const float* xsc = xs + hf * XSB2 + q * XSC;
        if (__all(okm == 0x1FFu)) {
#pragma unroll
            for (int kk = 0; kk < 9; kk++) {
                int A  = (int)(moff[kk] & 0xFFFFu);
                int Bo = (int)(moff[kk] >> 16);
                float p = xsc[A] * mw0[kk] + xsc[A + 1] * mw1[kk]
                        + xsc[Bo] * mw2[kk] + xsc[Bo + 1] * mw3[kk];
                Pl[lpix * S_ + kk * 8 + hf * 4 + q] = (_Float16)p;
            }
        } else {
            // rare big-offset fallback: gather from global (clamped, valid)
            const float* xc = xb + ((long)(4 * h + q) << 14);
#pragma unroll
            for (int kk = 0; kk < 9; kk++) {
                int ky = kk / 3, kx = kk - 3 * ky;
                float dy = offs_lds[(2 * kk) * 64 + lpix];
                float dx = offs_lds[(2 * kk + 1) * 64 + lpix];
                float py = (float)(ho - 1 + ky) + dy;
                float px = (float)(po - 1 + kx) + dx;
                int y0 = (int)floorf(py), x0 = (int)floorf(px);
                int cy0 = min(max(y0, 0), H_ - 1);
                int cy1 = min(max(y0 + 1, 0), H_ - 1);
                int xl  = min(max(x0, 0), W_ - 2);
                int ga = (cy0 << 7) + xl, gb = (cy1 << 7) + xl;
                float p = xc[ga] * mw0[kk] + xc[ga + 1] * mw1[kk]
                        + xc[gb] * mw2[kk] + xc[gb + 1] * mw3[kk];
                Pl[lpix * S_ + kk * 8 + hf * 4 + q] = (_Float16)p;
            }
        }
    };

    for (int cc = 0; cc < 8; cc++) {
        const int h0 = 2 * cc;
        __syncthreads();                       // (A0) buf0 = half-stage h0 ready
        {                                      // issue h0+1 -> buf1 (always valid)
            float* dst = xs + XSB2;
            const float* srcb = xb + ((long)(h0 + 1) << 16);
#pragma unroll
            for (int s = 0; s < 2; s++) if (g2v[s])
                GLDS16(g2k[s] ? (srcb + g2o[s]) : zp, dst + 4 * (t + 256 * s));
        }
        sample_half(h0);
        __syncthreads();                       // (A1) buf1 = half-stage h0+1 ready
        if (cc < 7) {                          // issue h0+2 -> buf0
            const float* srcb = xb + ((long)(h0 + 2) << 16);
#pragma unroll
            for (int s = 0; s < 2; s++) if (g2v[s])
                GLDS16(g2k[s] ? (srcb + g2o[s]) : zp, xs + 4 * (t + 256 * s));
        }
        sample_half(h0 + 1);
        __syncthreads();                       // (B) Pl chunk cc complete
#pragma unroll
        for (int ks = 0; ks < 3; ks++) {
            half8v A0 = *(const half8v*)&wpad[(wm * 32 + lr) * WCOLS + cc * 96 + ks * 32 + q * 8];
            half8v A1 = *(const half8v*)&wpad[(wm * 32 + 16 + lr) * WCOLS + cc * 96 + ks * 32 + q * 8];
            half8v B0 = *(const half8v*)&Pl[(wn * 32 + lr) * S_ + ks * 32 + q * 8];
            half8v B1 = *(const half8v*)&Pl[(wn * 32 + 16 + lr) * S_ + ks * 32 + q * 8];
            a00 = __builtin_amdgcn_mfma_f32_16x16x32_f16(A0, B0, a00, 0, 0, 0);
            a01 = __builtin_amdgcn_mfma_f32_16x16x32_f16(A0, B1, a01, 0, 0, 0);
            a10 = __builtin_amdgcn_mfma_f32_16x16x32_f16(A1, B0, a10, 0, 0, 0);
            a11 = __builtin_amdgcn_mfma_f32_16x16x32_f16(A1, B1, a11, 0, 0, 0);
        }
    }

    // ---- epilogue ----
    const int pixc = hb * 64 + wn * 32 + lr;
#pragma unroll
    for (int r = 0; r < 4; r++) {
        int oc0 = wm * 32 + q * 4 + r;
        int oc1 = oc0 + 16;
        float* o0 = out + (((long)(b * OC_ + oc0)) << 14) + (ho << 7);
        float* o1 = out + (((long)(b * OC_ + oc1)) << 14) + (ho << 7);
        o0[pixc]      = a00[r] + bias[oc0];
        o0[pixc + 16] = a01[r] + bias[oc0];
        o1[pixc]      = a10[r] + bias[oc1];
        o1[pixc + 16] = a11[r] + bias[oc1];
    }
}

// ---------------------------------------------------------------------------
extern "C" void kernel_launch(void* const* d_in, const int* in_sizes, int n_in,
                              void* d_out, int out_size, void* d_ws, size_t ws_size,
                              hipStream_t stream) {
    const float* x  = (const float*)d_in[0];
    const float* wt = (const float*)d_in[1];
    const float* bi = (const float*)d_in[2];
    const float* ow = (const float*)d_in[3];
    const float* ob = (const float*)d_in[4];
    float* out = (float*)d_out;

    _Float16* wpad  = (_Float16*)d_ws;
    _Float16* w0pad = wpad + WPAD_HALFS;
    float*    zp    = (float*)((char*)d_ws + ZPAGE_BYTE);

    k0_prep<<<(OC_ * WCOLS + 32 * WCOLS + 255) / 256, 256, 0, stream>>>(wt, ow, wpad, w0pad, zp);
    k_fused<<<B_ * H_ * 2, 256, 0, stream>>>(x, wpad, w0pad, bi, ob, zp, out);
}